// Round 1
// baseline (622.761 us; speedup 1.0000x reference)
//
#include <hip/hip_runtime.h>

// Problem constants
#define IMG_H 512
#define IMG_W 512
#define HW (IMG_H * IMG_W)          // 262144 = 2^18
#define HW4 (HW / 4)                // 65536 = 2^16
#define NB 32                       // batch
#define NIMG (2 * NB)               // 32 pred + 32 true channel-1 images
#define NITER 10
#define TILE 32

static __device__ __forceinline__ float finf() { return __builtin_inff(); }

// Gather channel-1 slices of y_pred (images 0..31) and y_true (images 32..63)
// into one contiguous buffer. float4 vectorized; grid exactly covers data.
__global__ __launch_bounds__(256) void gather4(const float4* __restrict__ yp,
                                               const float4* __restrict__ yt,
                                               float4* __restrict__ dst) {
    int i = blockIdx.x * 256 + threadIdx.x;       // [0, NIMG*HW4)
    int img = i >> 16;                            // / HW4
    int r = i & (HW4 - 1);
    const float4* s;
    if (img < NB) s = yp + ((size_t)(2 * img + 1) << 16) + r;
    else          s = yt + ((size_t)(2 * (img - NB) + 1) << 16) + r;
    dst[i] = *s;
}

// One soft-skeletonize iteration:
//   mn = minpool3(x)  (OOB excluded)
//   x' = relu(x - relu(maxpool3(mn) - mn))   (maxpool OOB excluded)
// Block: 32x8 threads, 32x32 output tile, 36x36 input halo tile in LDS.
__global__ __launch_bounds__(256) void iter_kernel(const float* __restrict__ src,
                                                   float* __restrict__ dst) {
    __shared__ float s_in[36][37];   // +1 pad: conflict-free
    __shared__ float s_mn[34][35];

    const int img = blockIdx.z;
    const float* sp = src + (size_t)img * HW;
    float* dp       = dst + (size_t)img * HW;
    const int ox = blockIdx.x * TILE;
    const int oy = blockIdx.y * TILE;
    const int tid = threadIdx.y * 32 + threadIdx.x;

    // Stage 36x36 region centered on tile (halo 2). OOB -> +inf (min ignores).
    for (int idx = tid; idx < 36 * 36; idx += 256) {
        int ly = idx / 36, lx = idx - ly * 36;
        int gy = oy + ly - 2, gx = ox + lx - 2;
        float v = finf();
        if (gy >= 0 && gy < IMG_H && gx >= 0 && gx < IMG_W)
            v = sp[gy * IMG_W + gx];
        s_in[ly][lx] = v;
    }
    __syncthreads();

    // Min-pool into 34x34 (halo 1). Positions outside image -> -inf (max ignores).
    for (int idx = tid; idx < 34 * 34; idx += 256) {
        int my = idx / 34, mx = idx - my * 34;
        int gy = oy + my - 1, gx = ox + mx - 1;
        float m = -finf();
        if (gy >= 0 && gy < IMG_H && gx >= 0 && gx < IMG_W) {
            float a0 = fminf(fminf(s_in[my    ][mx], s_in[my    ][mx + 1]), s_in[my    ][mx + 2]);
            float a1 = fminf(fminf(s_in[my + 1][mx], s_in[my + 1][mx + 1]), s_in[my + 1][mx + 2]);
            float a2 = fminf(fminf(s_in[my + 2][mx], s_in[my + 2][mx + 1]), s_in[my + 2][mx + 2]);
            m = fminf(fminf(a0, a1), a2);
        }
        s_mn[my][mx] = m;
    }
    __syncthreads();

    // Max-pool of mn + contour + update; 4 rows per thread.
    const int px = threadIdx.x;
    #pragma unroll
    for (int r = 0; r < 4; ++r) {
        int py = threadIdx.y * 4 + r;
        float c = s_mn[py + 1][px + 1];
        float b0 = fmaxf(fmaxf(s_mn[py    ][px], s_mn[py    ][px + 1]), s_mn[py    ][px + 2]);
        float b1 = fmaxf(fmaxf(s_mn[py + 1][px], s_mn[py + 1][px + 1]), s_mn[py + 1][px + 2]);
        float b2 = fmaxf(fmaxf(s_mn[py + 2][px], s_mn[py + 2][px + 1]), s_mn[py + 2][px + 2]);
        float mx9 = fmaxf(fmaxf(b0, b1), b2);
        float contour = fmaxf(mx9 - c, 0.0f);
        float x = s_in[py + 2][px + 2];
        dp[(oy + py) * IMG_W + (ox + px)] = fmaxf(x - contour, 0.0f);
    }
}

// Four sums: acc[0]=sum(skelP*y_true_c1) acc[1]=sum(skelP)
//            acc[2]=sum(skelT*y_pred_c1) acc[3]=sum(skelT)
__global__ __launch_bounds__(256) void reduce_kernel(const float4* __restrict__ skel,
                                                     const float4* __restrict__ yp,
                                                     const float4* __restrict__ yt,
                                                     double* __restrict__ acc) {
    float s0 = 0.f, s1 = 0.f, s2 = 0.f, s3 = 0.f;
    const int stride = gridDim.x * 256;
    for (int i = blockIdx.x * 256 + threadIdx.x; i < NIMG * HW4; i += stride) {
        int img = i >> 16;
        int r = i & (HW4 - 1);
        float4 v = skel[i];
        if (img < NB) {
            float4 w = yt[((size_t)(2 * img + 1) << 16) + r];
            s0 += v.x * w.x + v.y * w.y + v.z * w.z + v.w * w.w;
            s1 += v.x + v.y + v.z + v.w;
        } else {
            float4 w = yp[((size_t)(2 * (img - NB) + 1) << 16) + r];
            s2 += v.x * w.x + v.y * w.y + v.z * w.z + v.w * w.w;
            s3 += v.x + v.y + v.z + v.w;
        }
    }
    // Wave (64-lane) reduction
    #pragma unroll
    for (int off = 32; off > 0; off >>= 1) {
        s0 += __shfl_down(s0, off);
        s1 += __shfl_down(s1, off);
        s2 += __shfl_down(s2, off);
        s3 += __shfl_down(s3, off);
    }
    __shared__ float ws[4][4];
    const int lane = threadIdx.x & 63;
    const int wave = threadIdx.x >> 6;
    if (lane == 0) {
        ws[wave][0] = s0; ws[wave][1] = s1; ws[wave][2] = s2; ws[wave][3] = s3;
    }
    __syncthreads();
    if (threadIdx.x == 0) {
        double t0 = 0, t1 = 0, t2 = 0, t3 = 0;
        #pragma unroll
        for (int w = 0; w < 4; ++w) {
            t0 += ws[w][0]; t1 += ws[w][1]; t2 += ws[w][2]; t3 += ws[w][3];
        }
        atomicAdd(&acc[0], t0);
        atomicAdd(&acc[1], t1);
        atomicAdd(&acc[2], t2);
        atomicAdd(&acc[3], t3);
    }
}

__global__ void finalize(const double* __restrict__ acc, float* __restrict__ out) {
    double tprec = (acc[0] + 1.0) / (acc[1] + 1.0);
    double tsens = (acc[2] + 1.0) / (acc[3] + 1.0);
    out[0] = (float)(1.0 - 2.0 * (tprec * tsens) / (tprec + tsens));
}

extern "C" void kernel_launch(void* const* d_in, const int* in_sizes, int n_in,
                              void* d_out, int out_size, void* d_ws, size_t ws_size,
                              hipStream_t stream) {
    (void)in_sizes; (void)n_in; (void)out_size; (void)ws_size;
    const float* yp = (const float*)d_in[0];
    const float* yt = (const float*)d_in[1];
    float* out = (float*)d_out;

    // Workspace layout: bufA (64 MB) | bufB (64 MB) | acc (4 doubles)
    float* bufA = (float*)d_ws;
    float* bufB = bufA + (size_t)NIMG * HW;
    double* acc = (double*)(bufB + (size_t)NIMG * HW);

    hipMemsetAsync(acc, 0, 4 * sizeof(double), stream);

    gather4<<<(NIMG * HW4) / 256, 256, 0, stream>>>(
        (const float4*)yp, (const float4*)yt, (float4*)bufA);

    float* cur = bufA;
    float* nxt = bufB;
    for (int it = 0; it < NITER; ++it) {
        iter_kernel<<<dim3(IMG_W / TILE, IMG_H / TILE, NIMG), dim3(32, 8), 0, stream>>>(cur, nxt);
        float* t = cur; cur = nxt; nxt = t;
    }

    reduce_kernel<<<1024, 256, 0, stream>>>(
        (const float4*)cur, (const float4*)yp, (const float4*)yt, acc);
    finalize<<<1, 1, 0, stream>>>(acc, out);
}

// Round 2
// 488.479 us; speedup vs baseline: 1.2749x; 1.2749x over previous
//
#include <hip/hip_runtime.h>

// Problem constants
#define IMG 512
#define HW (IMG * IMG)        // 262144
#define NB 32
#define NIMG 64               // 32 pred-c1 + 32 true-c1 images
#define TILE 64               // output tile
#define RROWS 84              // staged rows   = 64 + 2*10
#define LSTR 88               // staged cols & LDS row stride (64 + 12 + 12, float4-aligned)
#define HALO_Y 10
#define HALO_X 12

#define INF __builtin_inff()

static __device__ __forceinline__ float min3f(float a, float b, float c) {
    return fminf(fminf(a, b), c);
}
static __device__ __forceinline__ float max3f(float a, float b, float c) {
    return fmaxf(fmaxf(a, b), c);
}

// Stage an 84x88 halo region (origin: row oy-10, col ox-12) into LDS.
// OOB pixels -> +inf (identity for min; masked to -inf for max later).
template <bool EDGE>
static __device__ __forceinline__ void stage_tile(const float* __restrict__ sp,
                                                  float* s_in, int ox, int oy, int tid) {
    for (int i = tid; i < RROWS * (LSTR / 4); i += 256) {
        int r = i / (LSTR / 4);
        int c4 = i - r * (LSTR / 4);
        int gy = oy - HALO_Y + r;
        int gx = ox - HALO_X + 4 * c4;
        float4 v;
        if (!EDGE) {
            v = *(const float4*)(sp + gy * IMG + gx);
        } else {
            bool ry = (unsigned)gy < (unsigned)IMG;
            if (ry && gx >= 0 && gx + 3 < IMG) {
                v = *(const float4*)(sp + gy * IMG + gx);
            } else {
                const float* row = sp + gy * IMG;
                v.x = (ry && (unsigned)(gx + 0) < (unsigned)IMG) ? row[gx + 0] : INF;
                v.y = (ry && (unsigned)(gx + 1) < (unsigned)IMG) ? row[gx + 1] : INF;
                v.z = (ry && (unsigned)(gx + 2) < (unsigned)IMG) ? row[gx + 2] : INF;
                v.w = (ry && (unsigned)(gx + 3) < (unsigned)IMG) ? row[gx + 3] : INF;
            }
        }
        *(float4*)(s_in + r * LSTR + 4 * c4) = v;
    }
}

// 5 fused soft-skeletonize iterations on the staged tile (in-place in s_in).
// Fixed-region passes: mn over rows 1..82, update over rows 2..81, all 22
// col-chunks. Validity shrinks 2/iter; after 5 iters center rows 10..73 /
// cols 12..75 (the 64x64 output) are exact.
template <bool EDGE>
static __device__ __forceinline__ void skel5(float* s_in, float* s_mn,
                                             int ox, int oy, int tid) {
    for (int j = 0; j < 5; ++j) {
        // ---- min-pool pass: row pairs r0, r0+1 for r0 = 1,3,...,81 ----
        for (int p = tid; p < 41 * 22; p += 256) {
            int pr = p / 22, c4 = p - pr * 22;
            int r0 = 1 + 2 * pr;
            int cb = 4 * c4;
            int il = (c4 == 0) ? 0 : cb - 1;
            int ir = (c4 == 21) ? (LSTR - 1) : cb + 4;
            float4 rm[4];
#pragma unroll
            for (int k = 0; k < 4; ++k) {
                const float* row = s_in + (r0 - 1 + k) * LSTR;
                float4 v = *(const float4*)(row + cb);
                float lf = row[il], rt = row[ir];
                rm[k].x = min3f(lf, v.x, v.y);
                rm[k].y = min3f(v.x, v.y, v.z);
                rm[k].z = min3f(v.y, v.z, v.w);
                rm[k].w = min3f(v.z, v.w, rt);
            }
            float4 m0, m1;
            m0.x = min3f(rm[0].x, rm[1].x, rm[2].x);
            m0.y = min3f(rm[0].y, rm[1].y, rm[2].y);
            m0.z = min3f(rm[0].z, rm[1].z, rm[2].z);
            m0.w = min3f(rm[0].w, rm[1].w, rm[2].w);
            m1.x = min3f(rm[1].x, rm[2].x, rm[3].x);
            m1.y = min3f(rm[1].y, rm[2].y, rm[3].y);
            m1.z = min3f(rm[1].z, rm[2].z, rm[3].z);
            m1.w = min3f(rm[1].w, rm[2].w, rm[3].w);
            if (EDGE) {
                // OOB image positions must be -inf so maxpool ignores them.
                int gxb = ox - HALO_X + cb;
                int gy0 = oy - HALO_Y + r0;
                bool cx0 = (unsigned)(gxb + 0) < (unsigned)IMG;
                bool cx1 = (unsigned)(gxb + 1) < (unsigned)IMG;
                bool cx2 = (unsigned)(gxb + 2) < (unsigned)IMG;
                bool cx3 = (unsigned)(gxb + 3) < (unsigned)IMG;
                bool ry0 = (unsigned)gy0 < (unsigned)IMG;
                bool ry1 = (unsigned)(gy0 + 1) < (unsigned)IMG;
                m0.x = (ry0 && cx0) ? m0.x : -INF;
                m0.y = (ry0 && cx1) ? m0.y : -INF;
                m0.z = (ry0 && cx2) ? m0.z : -INF;
                m0.w = (ry0 && cx3) ? m0.w : -INF;
                m1.x = (ry1 && cx0) ? m1.x : -INF;
                m1.y = (ry1 && cx1) ? m1.y : -INF;
                m1.z = (ry1 && cx2) ? m1.z : -INF;
                m1.w = (ry1 && cx3) ? m1.w : -INF;
            }
            *(float4*)(s_mn + r0 * LSTR + cb) = m0;
            *(float4*)(s_mn + (r0 + 1) * LSTR + cb) = m1;
        }
        __syncthreads();
        // ---- max-pool + contour + update pass: row pairs r0 = 2,4,...,80 ----
        for (int p = tid; p < 40 * 22; p += 256) {
            int pr = p / 22, c4 = p - pr * 22;
            int r0 = 2 + 2 * pr;
            int cb = 4 * c4;
            int il = (c4 == 0) ? 0 : cb - 1;
            int ir = (c4 == 21) ? (LSTR - 1) : cb + 4;
            float4 rx[4];
            float4 mc[2];
#pragma unroll
            for (int k = 0; k < 4; ++k) {
                const float* row = s_mn + (r0 - 1 + k) * LSTR;
                float4 v = *(const float4*)(row + cb);
                float lf = row[il], rt = row[ir];
                rx[k].x = max3f(lf, v.x, v.y);
                rx[k].y = max3f(v.x, v.y, v.z);
                rx[k].z = max3f(v.y, v.z, v.w);
                rx[k].w = max3f(v.z, v.w, rt);
                if (k == 1) mc[0] = v;
                if (k == 2) mc[1] = v;
            }
            float4 inA = *(const float4*)(s_in + r0 * LSTR + cb);
            float4 inB = *(const float4*)(s_in + (r0 + 1) * LSTR + cb);
            float4 o0, o1;
            o0.x = fmaxf(inA.x - fmaxf(max3f(rx[0].x, rx[1].x, rx[2].x) - mc[0].x, 0.f), 0.f);
            o0.y = fmaxf(inA.y - fmaxf(max3f(rx[0].y, rx[1].y, rx[2].y) - mc[0].y, 0.f), 0.f);
            o0.z = fmaxf(inA.z - fmaxf(max3f(rx[0].z, rx[1].z, rx[2].z) - mc[0].z, 0.f), 0.f);
            o0.w = fmaxf(inA.w - fmaxf(max3f(rx[0].w, rx[1].w, rx[2].w) - mc[0].w, 0.f), 0.f);
            o1.x = fmaxf(inB.x - fmaxf(max3f(rx[1].x, rx[2].x, rx[3].x) - mc[1].x, 0.f), 0.f);
            o1.y = fmaxf(inB.y - fmaxf(max3f(rx[1].y, rx[2].y, rx[3].y) - mc[1].y, 0.f), 0.f);
            o1.z = fmaxf(inB.z - fmaxf(max3f(rx[1].z, rx[2].z, rx[3].z) - mc[1].z, 0.f), 0.f);
            o1.w = fmaxf(inB.w - fmaxf(max3f(rx[1].w, rx[2].w, rx[3].w) - mc[1].w, 0.f), 0.f);
            if (EDGE) {
                // OOB image positions must stay +inf (identity for next minpool).
                int gxb = ox - HALO_X + cb;
                int gy0 = oy - HALO_Y + r0;
                bool cx0 = (unsigned)(gxb + 0) < (unsigned)IMG;
                bool cx1 = (unsigned)(gxb + 1) < (unsigned)IMG;
                bool cx2 = (unsigned)(gxb + 2) < (unsigned)IMG;
                bool cx3 = (unsigned)(gxb + 3) < (unsigned)IMG;
                bool ry0 = (unsigned)gy0 < (unsigned)IMG;
                bool ry1 = (unsigned)(gy0 + 1) < (unsigned)IMG;
                o0.x = (ry0 && cx0) ? o0.x : INF;
                o0.y = (ry0 && cx1) ? o0.y : INF;
                o0.z = (ry0 && cx2) ? o0.z : INF;
                o0.w = (ry0 && cx3) ? o0.w : INF;
                o1.x = (ry1 && cx0) ? o1.x : INF;
                o1.y = (ry1 && cx1) ? o1.y : INF;
                o1.z = (ry1 && cx2) ? o1.z : INF;
                o1.w = (ry1 && cx3) ? o1.w : INF;
            }
            *(float4*)(s_in + r0 * LSTR + cb) = o0;
            *(float4*)(s_in + (r0 + 1) * LSTR + cb) = o1;
        }
        __syncthreads();
    }
}

// Launch 1: read channel-1 slices of yp/yt directly (fused gather), run 5
// iterations, write 64x64 center to contiguous intermediate buffer.
__global__ __launch_bounds__(256, 2) void skel_first5(const float* __restrict__ yp,
                                                      const float* __restrict__ yt,
                                                      float* __restrict__ dst) {
    __shared__ float s_in[RROWS * LSTR];
    __shared__ float s_mn[RROWS * LSTR];
    const int img = blockIdx.z;
    const float* sp = (img < NB) ? yp + (size_t)(2 * img + 1) * HW
                                 : yt + (size_t)(2 * (img - NB) + 1) * HW;
    const int ox = blockIdx.x * TILE, oy = blockIdx.y * TILE;
    const int tid = threadIdx.x;
    const bool edge = (blockIdx.x == 0) | (blockIdx.x == 7) |
                      (blockIdx.y == 0) | (blockIdx.y == 7);
    if (edge) {
        stage_tile<true>(sp, s_in, ox, oy, tid);
        __syncthreads();
        skel5<true>(s_in, s_mn, ox, oy, tid);
    } else {
        stage_tile<false>(sp, s_in, ox, oy, tid);
        __syncthreads();
        skel5<false>(s_in, s_mn, ox, oy, tid);
    }
    float* dp = dst + (size_t)img * HW + oy * IMG + ox;
    for (int i = tid; i < 64 * 16; i += 256) {
        int r = i >> 4, c4 = i & 15;
        *(float4*)(dp + r * IMG + 4 * c4) =
            *(const float4*)(s_in + (HALO_Y + r) * LSTR + HALO_X + 4 * c4);
    }
}

// Launch 2: last 5 iterations + fused reduction (no skeleton write-out).
// acc[0]=sum(skelP*yt_c1) acc[1]=sum(skelP) acc[2]=sum(skelT*yp_c1) acc[3]=sum(skelT)
__global__ __launch_bounds__(256, 2) void skel_last5_reduce(const float* __restrict__ src,
                                                            const float* __restrict__ yp,
                                                            const float* __restrict__ yt,
                                                            double* __restrict__ acc) {
    __shared__ float s_in[RROWS * LSTR];
    __shared__ float s_mn[RROWS * LSTR];
    __shared__ float red[8];
    const int img = blockIdx.z;
    const float* sp = src + (size_t)img * HW;
    const int ox = blockIdx.x * TILE, oy = blockIdx.y * TILE;
    const int tid = threadIdx.x;
    const bool edge = (blockIdx.x == 0) | (blockIdx.x == 7) |
                      (blockIdx.y == 0) | (blockIdx.y == 7);
    if (edge) {
        stage_tile<true>(sp, s_in, ox, oy, tid);
        __syncthreads();
        skel5<true>(s_in, s_mn, ox, oy, tid);
    } else {
        stage_tile<false>(sp, s_in, ox, oy, tid);
        __syncthreads();
        skel5<false>(s_in, s_mn, ox, oy, tid);
    }
    // skel_pred pairs with y_true c1; skel_true pairs with y_pred c1.
    const float* wp = (img < NB) ? yt + (size_t)(2 * img + 1) * HW
                                 : yp + (size_t)(2 * (img - NB) + 1) * HW;
    float spd = 0.f, sv = 0.f;
    for (int i = tid; i < 64 * 16; i += 256) {
        int r = i >> 4, c4 = i & 15;
        float4 s = *(const float4*)(s_in + (HALO_Y + r) * LSTR + HALO_X + 4 * c4);
        float4 w = *(const float4*)(wp + (size_t)(oy + r) * IMG + ox + 4 * c4);
        spd += s.x * w.x + s.y * w.y + s.z * w.z + s.w * w.w;
        sv += s.x + s.y + s.z + s.w;
    }
#pragma unroll
    for (int off = 32; off; off >>= 1) {
        spd += __shfl_down(spd, off);
        sv += __shfl_down(sv, off);
    }
    const int lane = tid & 63, wv = tid >> 6;
    if (lane == 0) { red[wv] = spd; red[4 + wv] = sv; }
    __syncthreads();
    if (tid == 0) {
        double p = (double)red[0] + red[1] + red[2] + red[3];
        double v = (double)red[4] + red[5] + red[6] + red[7];
        int base = (img < NB) ? 0 : 2;
        atomicAdd(&acc[base], p);
        atomicAdd(&acc[base + 1], v);
    }
}

__global__ void finalize(const double* __restrict__ acc, float* __restrict__ out) {
    double tprec = (acc[0] + 1.0) / (acc[1] + 1.0);
    double tsens = (acc[2] + 1.0) / (acc[3] + 1.0);
    out[0] = (float)(1.0 - 2.0 * (tprec * tsens) / (tprec + tsens));
}

extern "C" void kernel_launch(void* const* d_in, const int* in_sizes, int n_in,
                              void* d_out, int out_size, void* d_ws, size_t ws_size,
                              hipStream_t stream) {
    (void)in_sizes; (void)n_in; (void)out_size; (void)ws_size;
    const float* yp = (const float*)d_in[0];
    const float* yt = (const float*)d_in[1];
    float* out = (float*)d_out;

    // Workspace: intermediate (64 MB) | acc (4 doubles)
    float* mid = (float*)d_ws;
    double* acc = (double*)(mid + (size_t)NIMG * HW);

    hipMemsetAsync(acc, 0, 4 * sizeof(double), stream);

    dim3 grid(IMG / TILE, IMG / TILE, NIMG);  // 8 x 8 x 64
    skel_first5<<<grid, 256, 0, stream>>>(yp, yt, mid);
    skel_last5_reduce<<<grid, 256, 0, stream>>>(mid, yp, yt, acc);
    finalize<<<1, 1, 0, stream>>>(acc, out);
}

// Round 3
// 275.614 us; speedup vs baseline: 2.2595x; 1.7723x over previous
//
#include <hip/hip_runtime.h>

#define IMG 512
#define HW (IMG * IMG)
#define NB 32
#define NIMG 64
#define BAND 32
#define NBAND (IMG / BAND)     // 16
#define NSTG 5                 // fused iterations per launch
#define HALO (2 * NSTG)        // 10
#define NROWS (BAND + 2 * HALO) // 52 streamed rows per block
#define INF __builtin_inff()

// One lane owns 8 contiguous columns: a = cols[8l..8l+3], b = cols[8l+4..8l+7].
struct Row { float4 a, b; };

static __device__ __forceinline__ float min3f(float a, float b, float c) { return fminf(fminf(a, b), c); }
static __device__ __forceinline__ float max3f(float a, float b, float c) { return fmaxf(fmaxf(a, b), c); }

static __device__ __forceinline__ Row splat(float v) {
    Row r;
    r.a = make_float4(v, v, v, v);
    r.b = make_float4(v, v, v, v);
    return r;
}

static __device__ __forceinline__ Row rmin3(const Row& x, const Row& y, const Row& z) {
    Row o;
    const float* px = (const float*)&x;
    const float* py = (const float*)&y;
    const float* pz = (const float*)&z;
    float* po = (float*)&o;
#pragma unroll
    for (int i = 0; i < 8; ++i) po[i] = min3f(px[i], py[i], pz[i]);
    return o;
}

static __device__ __forceinline__ Row rmax3(const Row& x, const Row& y, const Row& z) {
    Row o;
    const float* px = (const float*)&x;
    const float* py = (const float*)&y;
    const float* pz = (const float*)&z;
    float* po = (float*)&o;
#pragma unroll
    for (int i = 0; i < 8; ++i) po[i] = max3f(px[i], py[i], pz[i]);
    return o;
}

// Horizontal 3-min across the full 512-wide row (lane edges via shuffle,
// image edges -> +inf identity).
static __device__ __forceinline__ Row hmin3(const Row& v, int lane) {
    float shl = __shfl_up(v.b.w, 1);    // prev lane's col 7
    float shr = __shfl_down(v.a.x, 1);  // next lane's col 0
    if (lane == 0) shl = INF;
    if (lane == 63) shr = INF;
    Row o;
    o.a.x = min3f(shl,   v.a.x, v.a.y);
    o.a.y = min3f(v.a.x, v.a.y, v.a.z);
    o.a.z = min3f(v.a.y, v.a.z, v.a.w);
    o.a.w = min3f(v.a.z, v.a.w, v.b.x);
    o.b.x = min3f(v.a.w, v.b.x, v.b.y);
    o.b.y = min3f(v.b.x, v.b.y, v.b.z);
    o.b.z = min3f(v.b.y, v.b.z, v.b.w);
    o.b.w = min3f(v.b.z, v.b.w, shr);
    return o;
}

static __device__ __forceinline__ Row hmax3(const Row& v, int lane) {
    float shl = __shfl_up(v.b.w, 1);
    float shr = __shfl_down(v.a.x, 1);
    if (lane == 0) shl = -INF;
    if (lane == 63) shr = -INF;
    Row o;
    o.a.x = max3f(shl,   v.a.x, v.a.y);
    o.a.y = max3f(v.a.x, v.a.y, v.a.z);
    o.a.z = max3f(v.a.y, v.a.z, v.a.w);
    o.a.w = max3f(v.a.z, v.a.w, v.b.x);
    o.b.x = max3f(v.a.w, v.b.x, v.b.y);
    o.b.y = max3f(v.b.x, v.b.y, v.b.z);
    o.b.z = max3f(v.b.y, v.b.z, v.b.w);
    o.b.w = max3f(v.b.z, v.b.w, shr);
    return o;
}

// One skeletonize stage step, streaming downward. At this step the stage's
// incoming row xin has image-row index t.
// State (phase P): x[P]=x[t-2], x[P^1]=x[t-1]; mn[P]=mn[t-3], mn[P^1]=mn[t-2].
// Produces the stage output for row t-2; OOB rows masked to the pipeline
// identities (mn -> -inf, x' -> +inf).
template <int P>
static __device__ __forceinline__ Row stage_step(Row (&x)[2], Row (&mn)[2],
                                                 const Row& xin, int t, int lane) {
    Row vmin = rmin3(x[P], x[P ^ 1], xin);     // vertical min, row t-1
    Row mnew = hmin3(vmin, lane);              // mn[t-1]
    if ((unsigned)(t - 1) >= IMG) mnew = splat(-INF);
    Row vmax = rmax3(mn[P], mn[P ^ 1], mnew);  // vertical max centered t-2
    Row mp = hmax3(vmax, lane);                // maxpool(mn) at row t-2
    Row out;
    {
        const float* pxc = (const float*)&x[P];       // x[t-2]
        const float* pmn = (const float*)&mn[P ^ 1];  // mn[t-2]
        const float* pmp = (const float*)&mp;
        float* po = (float*)&out;
#pragma unroll
        for (int i = 0; i < 8; ++i)
            po[i] = fmaxf(pxc[i] - fmaxf(pmp[i] - pmn[i], 0.f), 0.f);
    }
    if ((unsigned)(t - 2) >= IMG) out = splat(INF);
    x[P] = xin;    // becomes x[t'-1] next step
    mn[P] = mnew;  // becomes mn[t'-2] next step
    return out;
}

static __device__ __forceinline__ Row load_or_inf(const float* __restrict__ p, int r, int lane) {
    if ((unsigned)r >= IMG) return splat(INF);
    const float4* q = (const float4*)(p + (size_t)r * IMG + lane * 8);
    Row o;
    o.a = q[0];
    o.b = q[1];
    return o;
}

// ---------------- Launch 1: iterations 0..4, write intermediate ----------------
template <int P>
static __device__ __forceinline__ void phase_a(int r, Row (&pre)[2], Row (&x)[NSTG][2],
                                               Row (&mn)[NSTG][2], const float* __restrict__ src,
                                               float* __restrict__ dst, int B, int lane) {
    Row cur = pre[P];
    pre[P] = load_or_inf(src, r + 2, lane);   // prefetch 2 phases ahead
    cur = stage_step<P>(x[0], mn[0], cur, r, lane);
    cur = stage_step<P>(x[1], mn[1], cur, r - 2, lane);
    cur = stage_step<P>(x[2], mn[2], cur, r - 4, lane);
    cur = stage_step<P>(x[3], mn[3], cur, r - 6, lane);
    cur = stage_step<P>(x[4], mn[4], cur, r - 8, lane);
    const int v = r - HALO;
    if ((unsigned)(v - B) < BAND) {
        float4* q = (float4*)(dst + (size_t)v * IMG + lane * 8);
        q[0] = cur.a;
        q[1] = cur.b;
    }
}

__global__ __launch_bounds__(64, 1) void skel5_a(const float* __restrict__ yp,
                                                 const float* __restrict__ yt,
                                                 float* __restrict__ mid) {
    const int blk = blockIdx.x;
    const int img = blk >> 4, band = blk & (NBAND - 1);
    const float* src = (img < NB) ? yp + (size_t)(2 * img + 1) * HW
                                  : yt + (size_t)(2 * (img - NB) + 1) * HW;
    float* dst = mid + (size_t)img * HW;
    const int lane = threadIdx.x;
    const int B = band * BAND;

    Row x[NSTG][2], mn[NSTG][2];
#pragma unroll
    for (int j = 0; j < NSTG; ++j) {
        x[j][0] = splat(INF);  x[j][1] = splat(INF);
        mn[j][0] = splat(-INF); mn[j][1] = splat(-INF);
    }
    Row pre[2];
    pre[0] = load_or_inf(src, B - HALO, lane);
    pre[1] = load_or_inf(src, B - HALO + 1, lane);

#pragma unroll 1
    for (int rr = 0; rr < NROWS; rr += 2) {
        phase_a<0>(B - HALO + rr, pre, x, mn, src, dst, B, lane);
        phase_a<1>(B - HALO + rr + 1, pre, x, mn, src, dst, B, lane);
    }
}

// ---------- Launch 2: iterations 5..9 + fused reduction (no write-out) ----------
template <int P>
static __device__ __forceinline__ void phase_b(int r, Row (&pre)[2], Row (&wbuf)[2],
                                               Row (&x)[NSTG][2], Row (&mn)[NSTG][2],
                                               const float* __restrict__ src,
                                               const float* __restrict__ wp, int B, int lane,
                                               float& s_prod, float& s_val) {
    Row cur = pre[P];
    pre[P] = load_or_inf(src, r + 2, lane);
    cur = stage_step<P>(x[0], mn[0], cur, r, lane);
    cur = stage_step<P>(x[1], mn[1], cur, r - 2, lane);
    cur = stage_step<P>(x[2], mn[2], cur, r - 4, lane);
    cur = stage_step<P>(x[3], mn[3], cur, r - 6, lane);
    cur = stage_step<P>(x[4], mn[4], cur, r - 8, lane);
    const int v = r - HALO;
    if ((unsigned)(v - B) < BAND) {
        const Row w = wbuf[P];  // prefetched 2 phases ago
        const float* pc = (const float*)&cur;
        const float* pw = (const float*)&w;
#pragma unroll
        for (int i = 0; i < 8; ++i) {
            s_prod += pc[i] * pw[i];
            s_val += pc[i];
        }
    }
    const int vn = r + 2 - HALO;  // prefetch weight row for 2 phases ahead
    if ((unsigned)(vn - B) < BAND) {
        const float4* q = (const float4*)(wp + (size_t)vn * IMG + lane * 8);
        wbuf[P].a = q[0];
        wbuf[P].b = q[1];
    }
}

__global__ __launch_bounds__(64, 1) void skel5_b(const float* __restrict__ mid,
                                                 const float* __restrict__ yp,
                                                 const float* __restrict__ yt,
                                                 double* __restrict__ acc) {
    const int blk = blockIdx.x;
    const int img = blk >> 4, band = blk & (NBAND - 1);
    const float* src = mid + (size_t)img * HW;
    // skel(pred) pairs with y_true c1; skel(true) pairs with y_pred c1.
    const float* wp = (img < NB) ? yt + (size_t)(2 * img + 1) * HW
                                 : yp + (size_t)(2 * (img - NB) + 1) * HW;
    const int lane = threadIdx.x;
    const int B = band * BAND;

    Row x[NSTG][2], mn[NSTG][2];
#pragma unroll
    for (int j = 0; j < NSTG; ++j) {
        x[j][0] = splat(INF);  x[j][1] = splat(INF);
        mn[j][0] = splat(-INF); mn[j][1] = splat(-INF);
    }
    Row pre[2], wbuf[2];
    pre[0] = load_or_inf(src, B - HALO, lane);
    pre[1] = load_or_inf(src, B - HALO + 1, lane);
    wbuf[0] = splat(0.f);
    wbuf[1] = splat(0.f);

    float s_prod = 0.f, s_val = 0.f;
#pragma unroll 1
    for (int rr = 0; rr < NROWS; rr += 2) {
        phase_b<0>(B - HALO + rr, pre, wbuf, x, mn, src, wp, B, lane, s_prod, s_val);
        phase_b<1>(B - HALO + rr + 1, pre, wbuf, x, mn, src, wp, B, lane, s_prod, s_val);
    }
#pragma unroll
    for (int off = 32; off; off >>= 1) {
        s_prod += __shfl_down(s_prod, off);
        s_val += __shfl_down(s_val, off);
    }
    if (lane == 0) {
        const int base = (img < NB) ? 0 : 2;
        atomicAdd(&acc[base], (double)s_prod);
        atomicAdd(&acc[base + 1], (double)s_val);
    }
}

__global__ void finalize(const double* __restrict__ acc, float* __restrict__ out) {
    double tprec = (acc[0] + 1.0) / (acc[1] + 1.0);
    double tsens = (acc[2] + 1.0) / (acc[3] + 1.0);
    out[0] = (float)(1.0 - 2.0 * (tprec * tsens) / (tprec + tsens));
}

extern "C" void kernel_launch(void* const* d_in, const int* in_sizes, int n_in,
                              void* d_out, int out_size, void* d_ws, size_t ws_size,
                              hipStream_t stream) {
    (void)in_sizes; (void)n_in; (void)out_size; (void)ws_size;
    const float* yp = (const float*)d_in[0];
    const float* yt = (const float*)d_in[1];
    float* out = (float*)d_out;

    // Workspace: intermediate skeleton-after-5-iters (64 MB) | acc (4 doubles)
    float* mid = (float*)d_ws;
    double* acc = (double*)(mid + (size_t)NIMG * HW);

    hipMemsetAsync(acc, 0, 4 * sizeof(double), stream);

    const int grid = NIMG * NBAND;  // 1024 single-wave blocks
    skel5_a<<<grid, 64, 0, stream>>>(yp, yt, mid);
    skel5_b<<<grid, 64, 0, stream>>>(mid, yp, yt, acc);
    finalize<<<1, 1, 0, stream>>>(acc, out);
}

// Round 4
// 259.982 us; speedup vs baseline: 2.3954x; 1.0601x over previous
//
#include <hip/hip_runtime.h>

#define IMG 512
#define HW (IMG * IMG)
#define NB 32
#define NIMG 64
#define BAND 16
#define NBAND (IMG / BAND)              // 32
#define NSTG 5                          // fused iterations per launch
#define HALO (2 * NSTG)                 // 10
#define NSTEP ((BAND + 2 * HALO) / 2)   // 18 row-pair steps
#define INF __builtin_inff()

// One lane owns 8 contiguous columns: a = cols[8l..8l+3], b = cols[8l+4..8l+7].
struct Row { float4 a, b; };

static __device__ __forceinline__ float min3f(float a, float b, float c) { return fminf(fminf(a, b), c); }
static __device__ __forceinline__ float max3f(float a, float b, float c) { return fmaxf(fmaxf(a, b), c); }

static __device__ __forceinline__ Row splat(float v) {
    Row r;
    r.a = make_float4(v, v, v, v);
    r.b = make_float4(v, v, v, v);
    return r;
}

static __device__ __forceinline__ Row rmin3(const Row& x, const Row& y, const Row& z) {
    Row o;
    const float* px = (const float*)&x;
    const float* py = (const float*)&y;
    const float* pz = (const float*)&z;
    float* po = (float*)&o;
#pragma unroll
    for (int i = 0; i < 8; ++i) po[i] = min3f(px[i], py[i], pz[i]);
    return o;
}

static __device__ __forceinline__ Row rmax3(const Row& x, const Row& y, const Row& z) {
    Row o;
    const float* px = (const float*)&x;
    const float* py = (const float*)&y;
    const float* pz = (const float*)&z;
    float* po = (float*)&o;
#pragma unroll
    for (int i = 0; i < 8; ++i) po[i] = max3f(px[i], py[i], pz[i]);
    return o;
}

// Horizontal 3-min across the 512-wide row; lane edges via shuffle, image
// edges -> +inf identity.
static __device__ __forceinline__ Row hmin3(const Row& v, int lane) {
    float shl = __shfl_up(v.b.w, 1);
    float shr = __shfl_down(v.a.x, 1);
    if (lane == 0) shl = INF;
    if (lane == 63) shr = INF;
    Row o;
    o.a.x = min3f(shl,   v.a.x, v.a.y);
    o.a.y = min3f(v.a.x, v.a.y, v.a.z);
    o.a.z = min3f(v.a.y, v.a.z, v.a.w);
    o.a.w = min3f(v.a.z, v.a.w, v.b.x);
    o.b.x = min3f(v.a.w, v.b.x, v.b.y);
    o.b.y = min3f(v.b.x, v.b.y, v.b.z);
    o.b.z = min3f(v.b.y, v.b.z, v.b.w);
    o.b.w = min3f(v.b.z, v.b.w, shr);
    return o;
}

static __device__ __forceinline__ Row hmax3(const Row& v, int lane) {
    float shl = __shfl_up(v.b.w, 1);
    float shr = __shfl_down(v.a.x, 1);
    if (lane == 0) shl = -INF;
    if (lane == 63) shr = -INF;
    Row o;
    o.a.x = max3f(shl,   v.a.x, v.a.y);
    o.a.y = max3f(v.a.x, v.a.y, v.a.z);
    o.a.z = max3f(v.a.y, v.a.z, v.a.w);
    o.a.w = max3f(v.a.z, v.a.w, v.b.x);
    o.b.x = max3f(v.a.w, v.b.x, v.b.y);
    o.b.y = max3f(v.b.x, v.b.y, v.b.z);
    o.b.z = max3f(v.b.y, v.b.z, v.b.w);
    o.b.w = max3f(v.b.z, v.b.w, shr);
    return o;
}

// Row-paired skeletonize stage step. Entry state: x[0]=x[t-2], x[1]=x[t-1],
// mn[0]=mn[t-3], mn[1]=mn[t-2]. Inputs in0=x[t], in1=x[t+1]. On exit in0/in1
// hold this stage's outputs for rows (t-2, t-1), state advanced by 2 rows.
// The two hmin3 (and two hmax3) are independent -> shuffle latency overlaps.
template <bool EDGE>
static __device__ __forceinline__ void step2(Row (&x)[2], Row (&mn)[2],
                                             Row& in0, Row& in1, int t, int lane) {
    Row vmin0 = rmin3(x[0], x[1], in0);      // centered row t-1
    Row vmin1 = rmin3(x[1], in0, in1);       // centered row t
    Row mna = hmin3(vmin0, lane);            // mn[t-1]
    Row mnb = hmin3(vmin1, lane);            // mn[t]
    if (EDGE) {
        if ((unsigned)(t - 1) >= IMG) mna = splat(-INF);
        if ((unsigned)t >= IMG) mnb = splat(-INF);
    }
    Row vmax0 = rmax3(mn[0], mn[1], mna);    // centered t-2
    Row vmax1 = rmax3(mn[1], mna, mnb);      // centered t-1
    Row mp0 = hmax3(vmax0, lane);
    Row mp1 = hmax3(vmax1, lane);
    Row out0, out1;
    {
        const float* px0 = (const float*)&x[0];
        const float* px1 = (const float*)&x[1];
        const float* pm1 = (const float*)&mn[1];
        const float* pma = (const float*)&mna;
        const float* pp0 = (const float*)&mp0;
        const float* pp1 = (const float*)&mp1;
        float* po0 = (float*)&out0;
        float* po1 = (float*)&out1;
#pragma unroll
        for (int i = 0; i < 8; ++i) {
            po0[i] = fmaxf(px0[i] - fmaxf(pp0[i] - pm1[i], 0.f), 0.f);
            po1[i] = fmaxf(px1[i] - fmaxf(pp1[i] - pma[i], 0.f), 0.f);
        }
    }
    if (EDGE) {
        if ((unsigned)(t - 2) >= IMG) out0 = splat(INF);
        if ((unsigned)(t - 1) >= IMG) out1 = splat(INF);
    }
    x[0] = in0;  x[1] = in1;
    mn[0] = mna; mn[1] = mnb;
    in0 = out0;  in1 = out1;
}

static __device__ __forceinline__ Row load_or_inf(const float* __restrict__ p, int r, int lane) {
    if ((unsigned)r >= IMG) return splat(INF);
    const float4* q = (const float4*)(p + (size_t)r * IMG + lane * 8);
    Row o;
    o.a = q[0];
    o.b = q[1];
    return o;
}

// ---------------- Launch 1: iterations 0..4, write intermediate ----------------
template <bool EDGE>
static __device__ __forceinline__ void run_a(const float* __restrict__ src,
                                             float* __restrict__ dst, int B, int lane) {
    Row x[NSTG][2], mn[NSTG][2];
#pragma unroll
    for (int j = 0; j < NSTG; ++j) {
        x[j][0] = splat(INF);   x[j][1] = splat(INF);
        mn[j][0] = splat(-INF); mn[j][1] = splat(-INF);
    }
    Row pre0 = load_or_inf(src, B - HALO, lane);
    Row pre1 = load_or_inf(src, B - HALO + 1, lane);
#pragma unroll 1
    for (int k = 0; k < NSTEP; ++k) {
        const int t = B - HALO + 2 * k;
        Row in0 = pre0, in1 = pre1;
        const int tp = (k + 1 < NSTEP) ? t + 2 : -1;
        pre0 = load_or_inf(src, tp, lane);
        pre1 = load_or_inf(src, tp + 1, lane);
#pragma unroll
        for (int j = 0; j < NSTG; ++j)
            step2<EDGE>(x[j], mn[j], in0, in1, t - 2 * j, lane);
        const int v = t - HALO;
        if ((unsigned)(v - B) < BAND) {
            float4* q0 = (float4*)(dst + (size_t)v * IMG + lane * 8);
            q0[0] = in0.a; q0[1] = in0.b;
            float4* q1 = (float4*)(dst + (size_t)(v + 1) * IMG + lane * 8);
            q1[0] = in1.a; q1[1] = in1.b;
        }
    }
}

__global__ __launch_bounds__(64, 2) void skel5_a(const float* __restrict__ yp,
                                                 const float* __restrict__ yt,
                                                 float* __restrict__ mid) {
    const int blk = blockIdx.x;
    const int img = blk >> 5, band = blk & (NBAND - 1);
    const float* src = (img < NB) ? yp + (size_t)(2 * img + 1) * HW
                                  : yt + (size_t)(2 * (img - NB) + 1) * HW;
    float* dst = mid + (size_t)img * HW;
    const int lane = threadIdx.x;
    const int B = band * BAND;
    if (band == 0 || band == NBAND - 1) run_a<true>(src, dst, B, lane);
    else                                run_a<false>(src, dst, B, lane);
}

// ---------- Launch 2: iterations 5..9 + fused reduction (no write-out) ----------
template <bool EDGE>
static __device__ __forceinline__ void run_b(const float* __restrict__ src,
                                             const float* __restrict__ wp, int B, int lane,
                                             float& s_prod, float& s_val) {
    Row x[NSTG][2], mn[NSTG][2];
#pragma unroll
    for (int j = 0; j < NSTG; ++j) {
        x[j][0] = splat(INF);   x[j][1] = splat(INF);
        mn[j][0] = splat(-INF); mn[j][1] = splat(-INF);
    }
    Row pre0 = load_or_inf(src, B - HALO, lane);
    Row pre1 = load_or_inf(src, B - HALO + 1, lane);
#pragma unroll 1
    for (int k = 0; k < NSTEP; ++k) {
        const int t = B - HALO + 2 * k;
        Row in0 = pre0, in1 = pre1;
        const int tp = (k + 1 < NSTEP) ? t + 2 : -1;
        pre0 = load_or_inf(src, tp, lane);
        pre1 = load_or_inf(src, tp + 1, lane);
        const int v = t - HALO;
        const bool inband = (unsigned)(v - B) < BAND;
        // Issue weight loads before the stage chain; ~900 VALU cycles hide them.
        Row w0, w1;
        if (inband) {
            const float4* q0 = (const float4*)(wp + (size_t)v * IMG + lane * 8);
            w0.a = q0[0]; w0.b = q0[1];
            const float4* q1 = (const float4*)(wp + (size_t)(v + 1) * IMG + lane * 8);
            w1.a = q1[0]; w1.b = q1[1];
        }
#pragma unroll
        for (int j = 0; j < NSTG; ++j)
            step2<EDGE>(x[j], mn[j], in0, in1, t - 2 * j, lane);
        if (inband) {
            const float* p0 = (const float*)&in0;
            const float* p1 = (const float*)&in1;
            const float* q0 = (const float*)&w0;
            const float* q1 = (const float*)&w1;
#pragma unroll
            for (int i = 0; i < 8; ++i) {
                s_prod += p0[i] * q0[i] + p1[i] * q1[i];
                s_val += p0[i] + p1[i];
            }
        }
    }
}

__global__ __launch_bounds__(64, 2) void skel5_b(const float* __restrict__ mid,
                                                 const float* __restrict__ yp,
                                                 const float* __restrict__ yt,
                                                 double* __restrict__ acc) {
    const int blk = blockIdx.x;
    const int img = blk >> 5, band = blk & (NBAND - 1);
    const float* src = mid + (size_t)img * HW;
    // skel(pred) pairs with y_true c1; skel(true) pairs with y_pred c1.
    const float* wp = (img < NB) ? yt + (size_t)(2 * img + 1) * HW
                                 : yp + (size_t)(2 * (img - NB) + 1) * HW;
    const int lane = threadIdx.x;
    const int B = band * BAND;

    float s_prod = 0.f, s_val = 0.f;
    if (band == 0 || band == NBAND - 1) run_b<true>(src, wp, B, lane, s_prod, s_val);
    else                                run_b<false>(src, wp, B, lane, s_prod, s_val);

#pragma unroll
    for (int off = 32; off; off >>= 1) {
        s_prod += __shfl_down(s_prod, off);
        s_val += __shfl_down(s_val, off);
    }
    if (lane == 0) {
        const int base = (img < NB) ? 0 : 2;
        atomicAdd(&acc[base], (double)s_prod);
        atomicAdd(&acc[base + 1], (double)s_val);
    }
}

__global__ void finalize(const double* __restrict__ acc, float* __restrict__ out) {
    double tprec = (acc[0] + 1.0) / (acc[1] + 1.0);
    double tsens = (acc[2] + 1.0) / (acc[3] + 1.0);
    out[0] = (float)(1.0 - 2.0 * (tprec * tsens) / (tprec + tsens));
}

extern "C" void kernel_launch(void* const* d_in, const int* in_sizes, int n_in,
                              void* d_out, int out_size, void* d_ws, size_t ws_size,
                              hipStream_t stream) {
    (void)in_sizes; (void)n_in; (void)out_size; (void)ws_size;
    const float* yp = (const float*)d_in[0];
    const float* yt = (const float*)d_in[1];
    float* out = (float*)d_out;

    // Workspace: intermediate skeleton-after-5-iters (64 MB) | acc (4 doubles)
    float* mid = (float*)d_ws;
    double* acc = (double*)(mid + (size_t)NIMG * HW);

    hipMemsetAsync(acc, 0, 4 * sizeof(double), stream);

    const int grid = NIMG * NBAND;  // 2048 single-wave blocks = 2 waves/SIMD
    skel5_a<<<grid, 64, 0, stream>>>(yp, yt, mid);
    skel5_b<<<grid, 64, 0, stream>>>(mid, yp, yt, acc);
    finalize<<<1, 1, 0, stream>>>(acc, out);
}

// Round 5
// 259.598 us; speedup vs baseline: 2.3989x; 1.0015x over previous
//
#include <hip/hip_runtime.h>

#define IMG 512
#define HW (IMG * IMG)
#define NB 32
#define NIMG 64
#define BAND 16
#define NBAND (IMG / BAND)              // 32
#define NSTG 5                          // fused iterations per launch
#define HALO (2 * NSTG)                 // 10
#define NSTEP ((BAND + 2 * HALO) / 2)   // 18 row-pair steps
#define INF __builtin_inff()

// DPP whole-wave shift-by-1 (CDNA keeps Vega wave_shl/shr DPP controls).
// wave_shr1: lane i gets lane i-1's value; lane 0 gets `ident` (bound_ctrl=0
// keeps the old/dest operand for lanes with no valid source).
static __device__ __forceinline__ float dpp_from_prev(float v, float ident) {
    return __int_as_float(__builtin_amdgcn_update_dpp(
        __float_as_int(ident), __float_as_int(v), 0x138, 0xF, 0xF, false));
}
// wave_shl1: lane i gets lane i+1's value; lane 63 gets `ident`.
static __device__ __forceinline__ float dpp_from_next(float v, float ident) {
    return __int_as_float(__builtin_amdgcn_update_dpp(
        __float_as_int(ident), __float_as_int(v), 0x130, 0xF, 0xF, false));
}

// One lane owns 8 contiguous columns: a = cols[8l..8l+3], b = cols[8l+4..8l+7].
struct Row { float4 a, b; };

static __device__ __forceinline__ float min3f(float a, float b, float c) { return fminf(fminf(a, b), c); }
static __device__ __forceinline__ float max3f(float a, float b, float c) { return fmaxf(fmaxf(a, b), c); }

static __device__ __forceinline__ Row splat(float v) {
    Row r;
    r.a = make_float4(v, v, v, v);
    r.b = make_float4(v, v, v, v);
    return r;
}

static __device__ __forceinline__ Row rmin3(const Row& x, const Row& y, const Row& z) {
    Row o;
    const float* px = (const float*)&x;
    const float* py = (const float*)&y;
    const float* pz = (const float*)&z;
    float* po = (float*)&o;
#pragma unroll
    for (int i = 0; i < 8; ++i) po[i] = min3f(px[i], py[i], pz[i]);
    return o;
}

static __device__ __forceinline__ Row rmax3(const Row& x, const Row& y, const Row& z) {
    Row o;
    const float* px = (const float*)&x;
    const float* py = (const float*)&y;
    const float* pz = (const float*)&z;
    float* po = (float*)&o;
#pragma unroll
    for (int i = 0; i < 8; ++i) po[i] = max3f(px[i], py[i], pz[i]);
    return o;
}

// Horizontal 3-min across the 512-wide row. Lane-edge neighbors via DPP
// wave shifts; image edges get +inf identity for free from bound_ctrl.
static __device__ __forceinline__ Row hmin3(const Row& v) {
    float shl = dpp_from_prev(v.b.w, INF);
    float shr = dpp_from_next(v.a.x, INF);
    Row o;
    o.a.x = min3f(shl,   v.a.x, v.a.y);
    o.a.y = min3f(v.a.x, v.a.y, v.a.z);
    o.a.z = min3f(v.a.y, v.a.z, v.a.w);
    o.a.w = min3f(v.a.z, v.a.w, v.b.x);
    o.b.x = min3f(v.a.w, v.b.x, v.b.y);
    o.b.y = min3f(v.b.x, v.b.y, v.b.z);
    o.b.z = min3f(v.b.y, v.b.z, v.b.w);
    o.b.w = min3f(v.b.z, v.b.w, shr);
    return o;
}

static __device__ __forceinline__ Row hmax3(const Row& v) {
    float shl = dpp_from_prev(v.b.w, -INF);
    float shr = dpp_from_next(v.a.x, -INF);
    Row o;
    o.a.x = max3f(shl,   v.a.x, v.a.y);
    o.a.y = max3f(v.a.x, v.a.y, v.a.z);
    o.a.z = max3f(v.a.y, v.a.z, v.a.w);
    o.a.w = max3f(v.a.z, v.a.w, v.b.x);
    o.b.x = max3f(v.a.w, v.b.x, v.b.y);
    o.b.y = max3f(v.b.x, v.b.y, v.b.z);
    o.b.z = max3f(v.b.y, v.b.z, v.b.w);
    o.b.w = max3f(v.b.z, v.b.w, shr);
    return o;
}

// Row-paired skeletonize stage step. Entry state: x[0]=x[t-2], x[1]=x[t-1],
// mn[0]=mn[t-3], mn[1]=mn[t-2]. Inputs in0=x[t], in1=x[t+1]. On exit in0/in1
// hold this stage's outputs for rows (t-2, t-1), state advanced by 2 rows.
template <bool EDGE>
static __device__ __forceinline__ void step2(Row (&x)[2], Row (&mn)[2],
                                             Row& in0, Row& in1, int t) {
    Row vmin0 = rmin3(x[0], x[1], in0);      // centered row t-1
    Row vmin1 = rmin3(x[1], in0, in1);       // centered row t
    Row mna = hmin3(vmin0);                  // mn[t-1]
    Row mnb = hmin3(vmin1);                  // mn[t]
    if (EDGE) {
        if ((unsigned)(t - 1) >= IMG) mna = splat(-INF);
        if ((unsigned)t >= IMG) mnb = splat(-INF);
    }
    Row vmax0 = rmax3(mn[0], mn[1], mna);    // centered t-2
    Row vmax1 = rmax3(mn[1], mna, mnb);      // centered t-1
    Row mp0 = hmax3(vmax0);
    Row mp1 = hmax3(vmax1);
    Row out0, out1;
    {
        const float* px0 = (const float*)&x[0];
        const float* px1 = (const float*)&x[1];
        const float* pm1 = (const float*)&mn[1];
        const float* pma = (const float*)&mna;
        const float* pp0 = (const float*)&mp0;
        const float* pp1 = (const float*)&mp1;
        float* po0 = (float*)&out0;
        float* po1 = (float*)&out1;
#pragma unroll
        for (int i = 0; i < 8; ++i) {
            po0[i] = fmaxf(px0[i] - fmaxf(pp0[i] - pm1[i], 0.f), 0.f);
            po1[i] = fmaxf(px1[i] - fmaxf(pp1[i] - pma[i], 0.f), 0.f);
        }
    }
    if (EDGE) {
        if ((unsigned)(t - 2) >= IMG) out0 = splat(INF);
        if ((unsigned)(t - 1) >= IMG) out1 = splat(INF);
    }
    x[0] = in0;  x[1] = in1;
    mn[0] = mna; mn[1] = mnb;
    in0 = out0;  in1 = out1;
}

static __device__ __forceinline__ Row load_or_inf(const float* __restrict__ p, int r, int lane) {
    if ((unsigned)r >= IMG) return splat(INF);
    const float4* q = (const float4*)(p + (size_t)r * IMG + lane * 8);
    Row o;
    o.a = q[0];
    o.b = q[1];
    return o;
}

// ---------------- Launch 1: iterations 0..4, write intermediate ----------------
template <bool EDGE>
static __device__ __forceinline__ void run_a(const float* __restrict__ src,
                                             float* __restrict__ dst, int B, int lane) {
    Row x[NSTG][2], mn[NSTG][2];
#pragma unroll
    for (int j = 0; j < NSTG; ++j) {
        x[j][0] = splat(INF);   x[j][1] = splat(INF);
        mn[j][0] = splat(-INF); mn[j][1] = splat(-INF);
    }
    Row pre0 = load_or_inf(src, B - HALO, lane);
    Row pre1 = load_or_inf(src, B - HALO + 1, lane);
#pragma unroll 1
    for (int k = 0; k < NSTEP; ++k) {
        const int t = B - HALO + 2 * k;
        Row in0 = pre0, in1 = pre1;
        const int tp = (k + 1 < NSTEP) ? t + 2 : -1;
        pre0 = load_or_inf(src, tp, lane);
        pre1 = load_or_inf(src, tp + 1, lane);
#pragma unroll
        for (int j = 0; j < NSTG; ++j)
            step2<EDGE>(x[j], mn[j], in0, in1, t - 2 * j);
        const int v = t - HALO;
        if ((unsigned)(v - B) < BAND) {
            float4* q0 = (float4*)(dst + (size_t)v * IMG + lane * 8);
            q0[0] = in0.a; q0[1] = in0.b;
            float4* q1 = (float4*)(dst + (size_t)(v + 1) * IMG + lane * 8);
            q1[0] = in1.a; q1[1] = in1.b;
        }
    }
}

__global__ __launch_bounds__(64, 2) void skel5_a(const float* __restrict__ yp,
                                                 const float* __restrict__ yt,
                                                 float* __restrict__ mid) {
    const int blk = blockIdx.x;
    const int img = blk >> 5, band = blk & (NBAND - 1);
    const float* src = (img < NB) ? yp + (size_t)(2 * img + 1) * HW
                                  : yt + (size_t)(2 * (img - NB) + 1) * HW;
    float* dst = mid + (size_t)img * HW;
    const int lane = threadIdx.x;
    const int B = band * BAND;
    if (band == 0 || band == NBAND - 1) run_a<true>(src, dst, B, lane);
    else                                run_a<false>(src, dst, B, lane);
}

// ---------- Launch 2: iterations 5..9 + fused reduction (no write-out) ----------
template <bool EDGE>
static __device__ __forceinline__ void run_b(const float* __restrict__ src,
                                             const float* __restrict__ wp, int B, int lane,
                                             float& s_prod, float& s_val) {
    Row x[NSTG][2], mn[NSTG][2];
#pragma unroll
    for (int j = 0; j < NSTG; ++j) {
        x[j][0] = splat(INF);   x[j][1] = splat(INF);
        mn[j][0] = splat(-INF); mn[j][1] = splat(-INF);
    }
    Row pre0 = load_or_inf(src, B - HALO, lane);
    Row pre1 = load_or_inf(src, B - HALO + 1, lane);
#pragma unroll 1
    for (int k = 0; k < NSTEP; ++k) {
        const int t = B - HALO + 2 * k;
        Row in0 = pre0, in1 = pre1;
        const int tp = (k + 1 < NSTEP) ? t + 2 : -1;
        pre0 = load_or_inf(src, tp, lane);
        pre1 = load_or_inf(src, tp + 1, lane);
        const int v = t - HALO;
        const bool inband = (unsigned)(v - B) < BAND;
        // Issue weight loads before the stage chain; stage VALU hides them.
        Row w0, w1;
        if (inband) {
            const float4* q0 = (const float4*)(wp + (size_t)v * IMG + lane * 8);
            w0.a = q0[0]; w0.b = q0[1];
            const float4* q1 = (const float4*)(wp + (size_t)(v + 1) * IMG + lane * 8);
            w1.a = q1[0]; w1.b = q1[1];
        }
#pragma unroll
        for (int j = 0; j < NSTG; ++j)
            step2<EDGE>(x[j], mn[j], in0, in1, t - 2 * j);
        if (inband) {
            const float* p0 = (const float*)&in0;
            const float* p1 = (const float*)&in1;
            const float* q0 = (const float*)&w0;
            const float* q1 = (const float*)&w1;
#pragma unroll
            for (int i = 0; i < 8; ++i) {
                s_prod += p0[i] * q0[i] + p1[i] * q1[i];
                s_val += p0[i] + p1[i];
            }
        }
    }
}

__global__ __launch_bounds__(64, 2) void skel5_b(const float* __restrict__ mid,
                                                 const float* __restrict__ yp,
                                                 const float* __restrict__ yt,
                                                 double* __restrict__ acc) {
    const int blk = blockIdx.x;
    const int img = blk >> 5, band = blk & (NBAND - 1);
    const float* src = mid + (size_t)img * HW;
    // skel(pred) pairs with y_true c1; skel(true) pairs with y_pred c1.
    const float* wp = (img < NB) ? yt + (size_t)(2 * img + 1) * HW
                                 : yp + (size_t)(2 * (img - NB) + 1) * HW;
    const int lane = threadIdx.x;
    const int B = band * BAND;

    float s_prod = 0.f, s_val = 0.f;
    if (band == 0 || band == NBAND - 1) run_b<true>(src, wp, B, lane, s_prod, s_val);
    else                                run_b<false>(src, wp, B, lane, s_prod, s_val);

#pragma unroll
    for (int off = 32; off; off >>= 1) {
        s_prod += __shfl_down(s_prod, off);
        s_val += __shfl_down(s_val, off);
    }
    if (lane == 0) {
        const int base = (img < NB) ? 0 : 2;
        atomicAdd(&acc[base], (double)s_prod);
        atomicAdd(&acc[base + 1], (double)s_val);
    }
}

__global__ void finalize(const double* __restrict__ acc, float* __restrict__ out) {
    double tprec = (acc[0] + 1.0) / (acc[1] + 1.0);
    double tsens = (acc[2] + 1.0) / (acc[3] + 1.0);
    out[0] = (float)(1.0 - 2.0 * (tprec * tsens) / (tprec + tsens));
}

extern "C" void kernel_launch(void* const* d_in, const int* in_sizes, int n_in,
                              void* d_out, int out_size, void* d_ws, size_t ws_size,
                              hipStream_t stream) {
    (void)in_sizes; (void)n_in; (void)out_size; (void)ws_size;
    const float* yp = (const float*)d_in[0];
    const float* yt = (const float*)d_in[1];
    float* out = (float*)d_out;

    // Workspace: intermediate skeleton-after-5-iters (64 MB) | acc (4 doubles)
    float* mid = (float*)d_ws;
    double* acc = (double*)(mid + (size_t)NIMG * HW);

    hipMemsetAsync(acc, 0, 4 * sizeof(double), stream);

    const int grid = NIMG * NBAND;  // 2048 single-wave blocks = 2 waves/SIMD
    skel5_a<<<grid, 64, 0, stream>>>(yp, yt, mid);
    skel5_b<<<grid, 64, 0, stream>>>(mid, yp, yt, acc);
    finalize<<<1, 1, 0, stream>>>(acc, out);
}